// Round 1
// baseline (1843.869 us; speedup 1.0000x reference)
//
#include <hip/hip_runtime.h>

#define N_NODES 8192
#define N_EDGES 262144
#define DIM 128

// ---------------- degree / normalization ----------------
__global__ void k_deg(const int* __restrict__ col, float* __restrict__ deg) {
    int e = blockIdx.x * blockDim.x + threadIdx.x;
    if (e < N_EDGES) atomicAdd(&deg[col[e]], 1.0f);
}

__global__ void k_dinv(const float* __restrict__ deg, float* __restrict__ dinv) {
    int i = blockIdx.x * blockDim.x + threadIdx.x;
    if (i < N_NODES) dinv[i] = rsqrtf(deg[i] + 1.0f);  // +1 = self-loop
}

// ---------------- dense GEMM: out[N,128] = x[N,128] @ W[128,128] ----------------
// W staged in LDS (64 KB). 256 threads: q = col-quad (32), rg = row-subgroup (8).
// 32 rows per block.
__global__ __launch_bounds__(256) void k_gemm(const float* __restrict__ x,
                                              const float* __restrict__ W,
                                              float* __restrict__ out) {
    __shared__ float4 Wl[128 * 32];  // Wl[k*32+q] = W[k, 4q..4q+3]
    int t = threadIdx.x;
    const float4* W4 = (const float4*)W;
    for (int i = t; i < 128 * 32; i += 256) Wl[i] = W4[i];
    __syncthreads();

    int q  = t & 31;
    int rg = t >> 5;
    int row0 = blockIdx.x * 32;
    for (int p = 0; p < 4; ++p) {
        int row = row0 + p * 8 + rg;
        const float4* xr = (const float4*)(x + (size_t)row * DIM);
        float4 acc = {0.f, 0.f, 0.f, 0.f};
        #pragma unroll
        for (int k4 = 0; k4 < 32; ++k4) {
            float4 xv = xr[k4];
            float4 w0 = Wl[(k4 * 4 + 0) * 32 + q];
            float4 w1 = Wl[(k4 * 4 + 1) * 32 + q];
            float4 w2 = Wl[(k4 * 4 + 2) * 32 + q];
            float4 w3 = Wl[(k4 * 4 + 3) * 32 + q];
            acc.x += xv.x * w0.x + xv.y * w1.x + xv.z * w2.x + xv.w * w3.x;
            acc.y += xv.x * w0.y + xv.y * w1.y + xv.z * w2.y + xv.w * w3.y;
            acc.z += xv.x * w0.z + xv.y * w1.z + xv.z * w2.z + xv.w * w3.z;
            acc.w += xv.x * w0.w + xv.y * w1.w + xv.z * w2.w + xv.w * w3.w;
        }
        ((float4*)(out + (size_t)row * DIM))[q] = acc;
    }
}

// ---------------- edge scatter: acc[col] += dinv[row]*dinv[col] * h[row] ----------------
// 256 threads = 8 edges x 32 feature-quads per iteration; 256 edges per block.
__global__ __launch_bounds__(256) void k_scatter(const float* __restrict__ h,
                                                 const int* __restrict__ rows,
                                                 const int* __restrict__ cols,
                                                 const float* __restrict__ dinv,
                                                 float* acc) {
    int t  = threadIdx.x;
    int q  = t & 31;
    int eg = t >> 5;
    int e0 = blockIdx.x * 256;
    for (int it = 0; it < 32; ++it) {
        int e = e0 + it * 8 + eg;
        int r = rows[e];
        int c = cols[e];
        float n = dinv[r] * dinv[c];
        float4 hv = ((const float4*)(h + (size_t)r * DIM))[q];
        float* dst = acc + (size_t)c * DIM + q * 4;
        atomicAdd(dst + 0, n * hv.x);
        atomicAdd(dst + 1, n * hv.y);
        atomicAdd(dst + 2, n * hv.z);
        atomicAdd(dst + 3, n * hv.w);
    }
}

// ---------------- epilogue: out = acc + dinv^2 * h (self-loop) + b, optional relu ----------------
template <bool RELU>
__global__ __launch_bounds__(256) void k_post(const float* acc, const float* h,
                                              const float* __restrict__ dinv,
                                              const float* __restrict__ b,
                                              float* out) {
    int gid  = blockIdx.x * blockDim.x + threadIdx.x;  // 262144 threads
    int node = gid >> 5;
    int q    = gid & 31;
    float s = dinv[node];
    s = s * s;
    float4 a  = ((const float4*)(acc + (size_t)node * DIM))[q];
    float4 hv = ((const float4*)(h + (size_t)node * DIM))[q];
    float4 bv = ((const float4*)b)[q];
    float4 o;
    o.x = a.x + s * hv.x + bv.x;
    o.y = a.y + s * hv.y + bv.y;
    o.z = a.z + s * hv.z + bv.z;
    o.w = a.w + s * hv.w + bv.w;
    if (RELU) {
        o.x = fmaxf(o.x, 0.f); o.y = fmaxf(o.y, 0.f);
        o.z = fmaxf(o.z, 0.f); o.w = fmaxf(o.w, 0.f);
    }
    ((float4*)(out + (size_t)node * DIM))[q] = o;
}

// ---------------- fc1: facc[128] += flat[1048576] @ fc1_w[1048576,128] ----------------
// 2048 blocks x 512 rows. Coalesced float4 weight reads (4 KB/iter/block).
__global__ __launch_bounds__(256) void k_fc1(const float* __restrict__ flat,
                                             const float* __restrict__ w,
                                             float* __restrict__ facc) {
    __shared__ float4 red[256];
    int t  = threadIdx.x;
    int q  = t & 31;
    int rg = t >> 5;
    int base = blockIdx.x * 512;
    float4 acc = {0.f, 0.f, 0.f, 0.f};
    for (int it = 0; it < 64; ++it) {
        int r = base + it * 8 + rg;
        float fv = flat[r];
        float4 wv = ((const float4*)(w + (size_t)r * DIM))[q];
        acc.x += fv * wv.x;
        acc.y += fv * wv.y;
        acc.z += fv * wv.z;
        acc.w += fv * wv.w;
    }
    red[t] = acc;
    __syncthreads();
    if (t < 32) {
        float4 s = red[t];
        for (int g = 1; g < 8; ++g) {
            float4 v = red[g * 32 + t];
            s.x += v.x; s.y += v.y; s.z += v.z; s.w += v.w;
        }
        float* dst = facc + t * 4;
        atomicAdd(dst + 0, s.x);
        atomicAdd(dst + 1, s.y);
        atomicAdd(dst + 2, s.z);
        atomicAdd(dst + 3, s.w);
    }
}

// ---------------- MLP tail: relu(facc+b1) @ fc2 -> relu -> @ fc3 -> scalar ----------------
__global__ __launch_bounds__(128) void k_tail(const float* __restrict__ facc,
                                              const float* __restrict__ fc1_b,
                                              const float* __restrict__ fc2_w,
                                              const float* __restrict__ fc2_b,
                                              const float* __restrict__ fc3_w,
                                              const float* __restrict__ fc3_b,
                                              float* __restrict__ out) {
    __shared__ float h1[128], red[128];
    int j = threadIdx.x;
    h1[j] = fmaxf(facc[j] + fc1_b[j], 0.f);
    __syncthreads();
    float a = 0.f;
    #pragma unroll 8
    for (int k = 0; k < 128; ++k) a += h1[k] * fc2_w[k * 128 + j];
    float h2 = fmaxf(a + fc2_b[j], 0.f);
    red[j] = h2 * fc3_w[j];
    __syncthreads();
    if (j == 0) {
        float s = 0.f;
        for (int k = 0; k < 128; ++k) s += red[k];
        out[0] = s + fc3_b[0];
    }
}

extern "C" void kernel_launch(void* const* d_in, const int* in_sizes, int n_in,
                              void* d_out, int out_size, void* d_ws, size_t ws_size,
                              hipStream_t stream) {
    const float* x     = (const float*)d_in[0];
    const int*   ei    = (const int*)d_in[1];
    const float* W1    = (const float*)d_in[2];
    const float* b1    = (const float*)d_in[3];
    const float* W2    = (const float*)d_in[4];
    const float* b2    = (const float*)d_in[5];
    const float* fc1_w = (const float*)d_in[6];
    const float* fc1_b = (const float*)d_in[7];
    const float* fc2_w = (const float*)d_in[8];
    const float* fc2_b = (const float*)d_in[9];
    const float* fc3_w = (const float*)d_in[10];
    const float* fc3_b = (const float*)d_in[11];
    const int* rows = ei;             // edge_index[0] = sources
    const int* cols = ei + N_EDGES;   // edge_index[1] = targets

    float* buf0 = (float*)d_ws;            // h (x@W) buffer, 1M floats
    float* buf1 = buf0 + N_NODES * DIM;    // conv accumulator / e, 1M floats
    float* deg  = buf1 + N_NODES * DIM;    // 8192
    float* dinv = deg + N_NODES;           // 8192
    float* facc = dinv + N_NODES;          // 128
    float* out  = (float*)d_out;

    hipMemsetAsync(deg, 0, N_NODES * sizeof(float), stream);
    hipMemsetAsync(facc, 0, DIM * sizeof(float), stream);
    hipMemsetAsync(buf1, 0, (size_t)N_NODES * DIM * sizeof(float), stream);

    k_deg<<<N_EDGES / 256, 256, 0, stream>>>(cols, deg);
    k_dinv<<<N_NODES / 256, 256, 0, stream>>>(deg, dinv);

    // ---- GCN layer 1: e1 = relu(conv(x, W1, b1)) ----
    k_gemm<<<N_NODES / 32, 256, 0, stream>>>(x, W1, buf0);
    k_scatter<<<N_EDGES / 256, 256, 0, stream>>>(buf0, rows, cols, dinv, buf1);
    k_post<true><<<(N_NODES * 32) / 256, 256, 0, stream>>>(buf1, buf0, dinv, b1, buf1);

    // ---- GCN layer 2: e2 = conv(e1, W2, b2) ----
    k_gemm<<<N_NODES / 32, 256, 0, stream>>>(buf1, W2, buf0);
    hipMemsetAsync(buf1, 0, (size_t)N_NODES * DIM * sizeof(float), stream); // after gemm (stream-ordered)
    k_scatter<<<N_EDGES / 256, 256, 0, stream>>>(buf0, rows, cols, dinv, buf1);
    k_post<false><<<(N_NODES * 32) / 256, 256, 0, stream>>>(buf1, buf0, dinv, b2, buf1);

    // ---- MLP head ----
    k_fc1<<<2048, 256, 0, stream>>>(buf1, fc1_w, facc);
    k_tail<<<1, 128, 0, stream>>>(facc, fc1_b, fc2_w, fc2_b, fc3_w, fc3_b, out);
}

// Round 2
// 996.168 us; speedup vs baseline: 1.8510x; 1.8510x over previous
//
#include <hip/hip_runtime.h>

#define N_NODES 8192
#define N_EDGES 262144
#define DIM 128

// ---------------- degree histogram (int) ----------------
__global__ void k_deg(const int* __restrict__ col, int* __restrict__ deg) {
    int e = blockIdx.x * blockDim.x + threadIdx.x;
    if (e < N_EDGES) atomicAdd(&deg[col[e]], 1);
}

__global__ void k_dinv(const int* __restrict__ deg, float* __restrict__ dinv) {
    int i = blockIdx.x * blockDim.x + threadIdx.x;
    if (i < N_NODES) dinv[i] = rsqrtf((float)deg[i] + 1.0f);  // +1 = self-loop
}

// ---------------- exclusive prefix scan of deg[8192] -> rowptr[8193] ----------------
__global__ __launch_bounds__(1024) void k_scan(const int* __restrict__ deg,
                                               int* __restrict__ rowptr) {
    __shared__ int part[1024];
    int t = threadIdx.x;
    int base = t * 8;
    int v[8];
    int s = 0;
    #pragma unroll
    for (int i = 0; i < 8; ++i) { v[i] = s; s += deg[base + i]; }
    part[t] = s;
    __syncthreads();
    for (int off = 1; off < 1024; off <<= 1) {
        int x = (t >= off) ? part[t - off] : 0;
        __syncthreads();
        part[t] += x;
        __syncthreads();
    }
    int basesum = (t == 0) ? 0 : part[t - 1];
    #pragma unroll
    for (int i = 0; i < 8; ++i) rowptr[base + i] = basesum + v[i];
    if (t == 1023) rowptr[8192] = part[1023];
}

// ---------------- CSR fill: srcs grouped by target node ----------------
__global__ void k_fill(const int* __restrict__ rows, const int* __restrict__ cols,
                       const int* __restrict__ rowptr, int* __restrict__ cnt,
                       int* __restrict__ srcs) {
    int e = blockIdx.x * blockDim.x + threadIdx.x;
    if (e < N_EDGES) {
        int c = cols[e];
        int p = atomicAdd(&cnt[c], 1);
        srcs[rowptr[c] + p] = rows[e];
    }
}

// ---------------- dense GEMM: out[row] = dinv[row] * (x[row] @ W) ----------------
__global__ __launch_bounds__(256) void k_gemm(const float* __restrict__ x,
                                              const float* __restrict__ W,
                                              const float* __restrict__ dinv,
                                              float* __restrict__ out) {
    __shared__ float4 Wl[128 * 32];  // Wl[k*32+q] = W[k, 4q..4q+3]
    int t = threadIdx.x;
    const float4* W4 = (const float4*)W;
    for (int i = t; i < 128 * 32; i += 256) Wl[i] = W4[i];
    __syncthreads();

    int q  = t & 31;
    int rg = t >> 5;
    int row0 = blockIdx.x * 32;
    for (int p = 0; p < 4; ++p) {
        int row = row0 + p * 8 + rg;
        const float4* xr = (const float4*)(x + (size_t)row * DIM);
        float4 acc = {0.f, 0.f, 0.f, 0.f};
        #pragma unroll
        for (int k4 = 0; k4 < 32; ++k4) {
            float4 xv = xr[k4];
            float4 w0 = Wl[(k4 * 4 + 0) * 32 + q];
            float4 w1 = Wl[(k4 * 4 + 1) * 32 + q];
            float4 w2 = Wl[(k4 * 4 + 2) * 32 + q];
            float4 w3 = Wl[(k4 * 4 + 3) * 32 + q];
            acc.x += xv.x * w0.x + xv.y * w1.x + xv.z * w2.x + xv.w * w3.x;
            acc.y += xv.x * w0.y + xv.y * w1.y + xv.z * w2.y + xv.w * w3.y;
            acc.z += xv.x * w0.z + xv.y * w1.z + xv.z * w2.z + xv.w * w3.z;
            acc.w += xv.x * w0.w + xv.y * w1.w + xv.z * w2.w + xv.w * w3.w;
        }
        float s = dinv[row];
        acc.x *= s; acc.y *= s; acc.z *= s; acc.w *= s;
        ((float4*)(out + (size_t)row * DIM))[q] = acc;
    }
}

// ---------------- gather aggregation: out[c] = dinv[c]*(sum_{r in N(c)} h[r] + h[c]) + b ----------------
// h is pre-scaled by dinv[row]. One wave (64 lanes) per node, float2 per lane.
template <bool RELU>
__global__ __launch_bounds__(256) void k_gather(const float* __restrict__ h,
                                                const int* __restrict__ srcs,
                                                const int* __restrict__ rowptr,
                                                const float* __restrict__ dinv,
                                                const float* __restrict__ b,
                                                float* __restrict__ out) {
    int t = threadIdx.x;
    int lane = t & 63;
    int node = blockIdx.x * 4 + (t >> 6);
    const float2* H = (const float2*)h;
    int beg = rowptr[node];
    int end = rowptr[node + 1];
    float2 acc = H[(size_t)node * 64 + lane];  // self-loop term (h pre-scaled)
    int j = beg;
    for (; j + 1 < end; j += 2) {
        int r0 = srcs[j];
        int r1 = srcs[j + 1];
        float2 v0 = H[(size_t)r0 * 64 + lane];
        float2 v1 = H[(size_t)r1 * 64 + lane];
        acc.x += v0.x + v1.x;
        acc.y += v0.y + v1.y;
    }
    if (j < end) {
        int r = srcs[j];
        float2 v = H[(size_t)r * 64 + lane];
        acc.x += v.x;
        acc.y += v.y;
    }
    float s = dinv[node];
    float2 bv = ((const float2*)b)[lane];
    float2 o;
    o.x = s * acc.x + bv.x;
    o.y = s * acc.y + bv.y;
    if (RELU) { o.x = fmaxf(o.x, 0.f); o.y = fmaxf(o.y, 0.f); }
    ((float2*)(out + (size_t)node * DIM))[lane] = o;
}

// ---------------- fc1: facc[128] += flat[1048576] @ fc1_w[1048576,128] ----------------
__global__ __launch_bounds__(256) void k_fc1(const float* __restrict__ flat,
                                             const float* __restrict__ w,
                                             float* __restrict__ facc) {
    __shared__ float4 red[256];
    int t  = threadIdx.x;
    int q  = t & 31;
    int rg = t >> 5;
    int base = blockIdx.x * 512;
    float4 acc = {0.f, 0.f, 0.f, 0.f};
    for (int it = 0; it < 64; ++it) {
        int r = base + it * 8 + rg;
        float fv = flat[r];
        float4 wv = ((const float4*)(w + (size_t)r * DIM))[q];
        acc.x += fv * wv.x;
        acc.y += fv * wv.y;
        acc.z += fv * wv.z;
        acc.w += fv * wv.w;
    }
    red[t] = acc;
    __syncthreads();
    if (t < 32) {
        float4 s = red[t];
        for (int g = 1; g < 8; ++g) {
            float4 v = red[g * 32 + t];
            s.x += v.x; s.y += v.y; s.z += v.z; s.w += v.w;
        }
        float* dst = facc + t * 4;
        atomicAdd(dst + 0, s.x);
        atomicAdd(dst + 1, s.y);
        atomicAdd(dst + 2, s.z);
        atomicAdd(dst + 3, s.w);
    }
}

// ---------------- MLP tail ----------------
__global__ __launch_bounds__(128) void k_tail(const float* __restrict__ facc,
                                              const float* __restrict__ fc1_b,
                                              const float* __restrict__ fc2_w,
                                              const float* __restrict__ fc2_b,
                                              const float* __restrict__ fc3_w,
                                              const float* __restrict__ fc3_b,
                                              float* __restrict__ out) {
    __shared__ float h1[128], red[128];
    int j = threadIdx.x;
    h1[j] = fmaxf(facc[j] + fc1_b[j], 0.f);
    __syncthreads();
    float a = 0.f;
    #pragma unroll 8
    for (int k = 0; k < 128; ++k) a += h1[k] * fc2_w[k * 128 + j];
    float h2 = fmaxf(a + fc2_b[j], 0.f);
    red[j] = h2 * fc3_w[j];
    __syncthreads();
    if (j == 0) {
        float s = 0.f;
        for (int k = 0; k < 128; ++k) s += red[k];
        out[0] = s + fc3_b[0];
    }
}

extern "C" void kernel_launch(void* const* d_in, const int* in_sizes, int n_in,
                              void* d_out, int out_size, void* d_ws, size_t ws_size,
                              hipStream_t stream) {
    const float* x     = (const float*)d_in[0];
    const int*   ei    = (const int*)d_in[1];
    const float* W1    = (const float*)d_in[2];
    const float* b1    = (const float*)d_in[3];
    const float* W2    = (const float*)d_in[4];
    const float* b2    = (const float*)d_in[5];
    const float* fc1_w = (const float*)d_in[6];
    const float* fc1_b = (const float*)d_in[7];
    const float* fc2_w = (const float*)d_in[8];
    const float* fc2_b = (const float*)d_in[9];
    const float* fc3_w = (const float*)d_in[10];
    const float* fc3_b = (const float*)d_in[11];
    const int* rows = ei;             // edge_index[0] = sources
    const int* cols = ei + N_EDGES;   // edge_index[1] = targets

    float* buf0   = (float*)d_ws;                 // h_scaled, 1M floats (4 MB)
    float* buf1   = buf0 + (size_t)N_NODES * DIM; // conv out / e, 1M floats (4 MB)
    int*   degi   = (int*)(buf1 + (size_t)N_NODES * DIM); // 8192
    float* dinv   = (float*)(degi + N_NODES);     // 8192
    int*   rowptr = (int*)(dinv + N_NODES);       // 8193
    int*   cnt    = rowptr + N_NODES + 8;         // 8192 (padded)
    int*   srcs   = cnt + N_NODES;                // 262144
    float* facc   = (float*)(srcs + N_EDGES);     // 128
    float* out    = (float*)d_out;

    hipMemsetAsync(degi, 0, N_NODES * sizeof(int), stream);
    hipMemsetAsync(cnt, 0, N_NODES * sizeof(int), stream);
    hipMemsetAsync(facc, 0, DIM * sizeof(float), stream);

    // ---- graph preprocessing: degrees, norm, CSR by target ----
    k_deg<<<N_EDGES / 256, 256, 0, stream>>>(cols, degi);
    k_dinv<<<N_NODES / 256, 256, 0, stream>>>(degi, dinv);
    k_scan<<<1, 1024, 0, stream>>>(degi, rowptr);
    k_fill<<<N_EDGES / 256, 256, 0, stream>>>(rows, cols, rowptr, cnt, srcs);

    // ---- GCN layer 1: e1 = relu(conv(x, W1, b1)) ----
    k_gemm<<<N_NODES / 32, 256, 0, stream>>>(x, W1, dinv, buf0);
    k_gather<true><<<N_NODES / 4, 256, 0, stream>>>(buf0, srcs, rowptr, dinv, b1, buf1);

    // ---- GCN layer 2: e2 = conv(e1, W2, b2) ----
    k_gemm<<<N_NODES / 32, 256, 0, stream>>>(buf1, W2, dinv, buf0);
    k_gather<false><<<N_NODES / 4, 256, 0, stream>>>(buf0, srcs, rowptr, dinv, b2, buf1);

    // ---- MLP head ----
    k_fc1<<<2048, 256, 0, stream>>>(buf1, fc1_w, facc);
    k_tail<<<1, 128, 0, stream>>>(facc, fc1_b, fc2_w, fc2_b, fc3_w, fc3_b, out);
}

// Round 3
// 873.547 us; speedup vs baseline: 2.1108x; 1.1404x over previous
//
#include <hip/hip_runtime.h>

#define N_NODES 8192
#define N_EDGES 262144
#define DIM 128

// ---------------- degree histogram (int) ----------------
__global__ void k_deg(const int* __restrict__ col, int* __restrict__ deg) {
    int e = blockIdx.x * blockDim.x + threadIdx.x;
    if (e < N_EDGES) atomicAdd(&deg[col[e]], 1);
}

// ---------------- scan + dinv: rowptr[8193] = exclusive scan(deg), dinv = rsqrt(deg+1) ----------------
__global__ __launch_bounds__(1024) void k_scan(const int* __restrict__ deg,
                                               int* __restrict__ rowptr,
                                               float* __restrict__ dinv) {
    __shared__ int part[1024];
    int t = threadIdx.x;
    int base = t * 8;
    int v[8];
    int s = 0;
    #pragma unroll
    for (int i = 0; i < 8; ++i) {
        int d = deg[base + i];
        dinv[base + i] = rsqrtf((float)d + 1.0f);  // +1 = self-loop
        v[i] = s; s += d;
    }
    part[t] = s;
    __syncthreads();
    for (int off = 1; off < 1024; off <<= 1) {
        int x = (t >= off) ? part[t - off] : 0;
        __syncthreads();
        part[t] += x;
        __syncthreads();
    }
    int basesum = (t == 0) ? 0 : part[t - 1];
    #pragma unroll
    for (int i = 0; i < 8; ++i) rowptr[base + i] = basesum + v[i];
    if (t == 1023) rowptr[8192] = part[1023];
}

// ---------------- CSR fill: srcs grouped by target node ----------------
__global__ void k_fill(const int* __restrict__ rows, const int* __restrict__ cols,
                       const int* __restrict__ rowptr, int* __restrict__ cnt,
                       int* __restrict__ srcs) {
    int e = blockIdx.x * blockDim.x + threadIdx.x;
    if (e < N_EDGES) {
        int c = cols[e];
        int p = atomicAdd(&cnt[c], 1);
        srcs[rowptr[c] + p] = rows[e];
    }
}

// ---------------- dense GEMM: out[row] = dinv[row] * (x[row] @ W) ----------------
__global__ __launch_bounds__(256) void k_gemm(const float* __restrict__ x,
                                              const float* __restrict__ W,
                                              const float* __restrict__ dinv,
                                              float* __restrict__ out) {
    __shared__ float4 Wl[128 * 32];  // Wl[k*32+q] = W[k, 4q..4q+3]
    int t = threadIdx.x;
    const float4* W4 = (const float4*)W;
    for (int i = t; i < 128 * 32; i += 256) Wl[i] = W4[i];
    __syncthreads();

    int q  = t & 31;
    int rg = t >> 5;
    int row0 = blockIdx.x * 32;
    for (int p = 0; p < 4; ++p) {
        int row = row0 + p * 8 + rg;
        const float4* xr = (const float4*)(x + (size_t)row * DIM);
        float4 acc = {0.f, 0.f, 0.f, 0.f};
        #pragma unroll
        for (int k4 = 0; k4 < 32; ++k4) {
            float4 xv = xr[k4];
            float4 w0 = Wl[(k4 * 4 + 0) * 32 + q];
            float4 w1 = Wl[(k4 * 4 + 1) * 32 + q];
            float4 w2 = Wl[(k4 * 4 + 2) * 32 + q];
            float4 w3 = Wl[(k4 * 4 + 3) * 32 + q];
            acc.x += xv.x * w0.x + xv.y * w1.x + xv.z * w2.x + xv.w * w3.x;
            acc.y += xv.x * w0.y + xv.y * w1.y + xv.z * w2.y + xv.w * w3.y;
            acc.z += xv.x * w0.z + xv.y * w1.z + xv.z * w2.z + xv.w * w3.z;
            acc.w += xv.x * w0.w + xv.y * w1.w + xv.z * w2.w + xv.w * w3.w;
        }
        float s = dinv[row];
        acc.x *= s; acc.y *= s; acc.z *= s; acc.w *= s;
        ((float4*)(out + (size_t)row * DIM))[q] = acc;
    }
}

// ---------------- layer-1 gather: out[c] = relu(dinv[c]*(sum h[srcs] + h[c]) + b) ----------------
// h pre-scaled by dinv[row]. One wave per node, float2 per lane, 4-edge unroll.
__global__ __launch_bounds__(256) void k_gather(const float* __restrict__ h,
                                                const int* __restrict__ srcs,
                                                const int* __restrict__ rowptr,
                                                const float* __restrict__ dinv,
                                                const float* __restrict__ b,
                                                float* __restrict__ out) {
    int t = threadIdx.x;
    int lane = t & 63;
    int node = blockIdx.x * 4 + (t >> 6);
    const float2* H = (const float2*)h;
    int beg = rowptr[node];
    int end = rowptr[node + 1];
    float2 acc = H[(size_t)node * 64 + lane];  // self-loop term
    int j = beg;
    for (; j + 3 < end; j += 4) {
        int r0 = srcs[j], r1 = srcs[j + 1], r2 = srcs[j + 2], r3 = srcs[j + 3];
        float2 v0 = H[(size_t)r0 * 64 + lane];
        float2 v1 = H[(size_t)r1 * 64 + lane];
        float2 v2 = H[(size_t)r2 * 64 + lane];
        float2 v3 = H[(size_t)r3 * 64 + lane];
        acc.x += (v0.x + v1.x) + (v2.x + v3.x);
        acc.y += (v0.y + v1.y) + (v2.y + v3.y);
    }
    for (; j < end; ++j) {
        int r = srcs[j];
        float2 v = H[(size_t)r * 64 + lane];
        acc.x += v.x; acc.y += v.y;
    }
    float s = dinv[node];
    float2 bv = ((const float2*)b)[lane];
    float2 o;
    o.x = fmaxf(s * acc.x + bv.x, 0.f);
    o.y = fmaxf(s * acc.y + bv.y, 0.f);
    ((float2*)(out + (size_t)node * DIM))[lane] = o;
}

// ---------------- fused layer-2 gather + fc1 partial ----------------
// Per wave: e2 row for its node (gather, no relu) -> LDS, then stream this node's
// 128 fc1_w rows (float4, 2 rows/instr), reduce, 128 atomics per block.
__global__ __launch_bounds__(256) void k_gfc(const float* __restrict__ h,
                                             const int* __restrict__ srcs,
                                             const int* __restrict__ rowptr,
                                             const float* __restrict__ dinv,
                                             const float* __restrict__ b,
                                             const float* __restrict__ w,
                                             float* __restrict__ facc) {
    __shared__ float oL[4][128];
    __shared__ float4 red4[4][32];
    int t = threadIdx.x;
    int lane = t & 63;
    int wid = t >> 6;
    int node = blockIdx.x * 4 + wid;
    const float2* H = (const float2*)h;
    int beg = rowptr[node];
    int end = rowptr[node + 1];
    float2 acc = H[(size_t)node * 64 + lane];  // self-loop term
    int j = beg;
    for (; j + 3 < end; j += 4) {
        int r0 = srcs[j], r1 = srcs[j + 1], r2 = srcs[j + 2], r3 = srcs[j + 3];
        float2 v0 = H[(size_t)r0 * 64 + lane];
        float2 v1 = H[(size_t)r1 * 64 + lane];
        float2 v2 = H[(size_t)r2 * 64 + lane];
        float2 v3 = H[(size_t)r3 * 64 + lane];
        acc.x += (v0.x + v1.x) + (v2.x + v3.x);
        acc.y += (v0.y + v1.y) + (v2.y + v3.y);
    }
    for (; j < end; ++j) {
        int r = srcs[j];
        float2 v = H[(size_t)r * 64 + lane];
        acc.x += v.x; acc.y += v.y;
    }
    float s = dinv[node];
    float2 bv = ((const float2*)b)[lane];
    float2 o = { s * acc.x + bv.x, s * acc.y + bv.y };  // e2 row (no relu)
    ((float2*)oL[wid])[lane] = o;
    __syncthreads();

    // phase 2: facc[j] += sum_k e2[node,k] * w[node*128+k, j]
    int q  = lane & 31;   // j-quad
    int kh = lane >> 5;   // which of 2 rows this half-wave covers
    size_t rowbase = (size_t)node * 128;
    float4 a4 = {0.f, 0.f, 0.f, 0.f};
    #pragma unroll 8
    for (int k2 = 0; k2 < 64; ++k2) {
        int k = k2 * 2 + kh;
        float ok = oL[wid][k];
        float4 wr = ((const float4*)(w + (rowbase + k) * 128))[q];
        a4.x += ok * wr.x;
        a4.y += ok * wr.y;
        a4.z += ok * wr.z;
        a4.w += ok * wr.w;
    }
    a4.x += __shfl_xor(a4.x, 32);
    a4.y += __shfl_xor(a4.y, 32);
    a4.z += __shfl_xor(a4.z, 32);
    a4.w += __shfl_xor(a4.w, 32);
    if (lane < 32) red4[wid][q] = a4;
    __syncthreads();
    if (t < 128) {
        const float* rf = (const float*)red4;
        float val = (rf[t] + rf[128 + t]) + (rf[256 + t] + rf[384 + t]);
        atomicAdd(&facc[t], val);
    }
}

// ---------------- MLP tail ----------------
__global__ __launch_bounds__(128) void k_tail(const float* __restrict__ facc,
                                              const float* __restrict__ fc1_b,
                                              const float* __restrict__ fc2_w,
                                              const float* __restrict__ fc2_b,
                                              const float* __restrict__ fc3_w,
                                              const float* __restrict__ fc3_b,
                                              float* __restrict__ out) {
    __shared__ float h1[128], red[128];
    int j = threadIdx.x;
    h1[j] = fmaxf(facc[j] + fc1_b[j], 0.f);
    __syncthreads();
    float a = 0.f;
    #pragma unroll 8
    for (int k = 0; k < 128; ++k) a += h1[k] * fc2_w[k * 128 + j];
    float h2 = fmaxf(a + fc2_b[j], 0.f);
    red[j] = h2 * fc3_w[j];
    __syncthreads();
    if (j == 0) {
        float s = 0.f;
        for (int k = 0; k < 128; ++k) s += red[k];
        out[0] = s + fc3_b[0];
    }
}

extern "C" void kernel_launch(void* const* d_in, const int* in_sizes, int n_in,
                              void* d_out, int out_size, void* d_ws, size_t ws_size,
                              hipStream_t stream) {
    const float* x     = (const float*)d_in[0];
    const int*   ei    = (const int*)d_in[1];
    const float* W1    = (const float*)d_in[2];
    const float* b1    = (const float*)d_in[3];
    const float* W2    = (const float*)d_in[4];
    const float* b2    = (const float*)d_in[5];
    const float* fc1_w = (const float*)d_in[6];
    const float* fc1_b = (const float*)d_in[7];
    const float* fc2_w = (const float*)d_in[8];
    const float* fc2_b = (const float*)d_in[9];
    const float* fc3_w = (const float*)d_in[10];
    const float* fc3_b = (const float*)d_in[11];
    const int* rows = ei;             // edge_index[0] = sources
    const int* cols = ei + N_EDGES;   // edge_index[1] = targets

    float* buf0   = (float*)d_ws;                 // h_scaled, 1M floats (4 MB)
    float* buf1   = buf0 + (size_t)N_NODES * DIM; // e1, 1M floats (4 MB)
    int*   degi   = (int*)(buf1 + (size_t)N_NODES * DIM); // 8192 (zeroed)
    int*   cnt    = degi + N_NODES;               // 8192 (zeroed)
    float* facc   = (float*)(cnt + N_NODES);      // 128  (zeroed)
    float* dinv   = facc + DIM;                   // 8192
    int*   rowptr = (int*)(dinv + N_NODES);       // 8193
    int*   srcs   = rowptr + N_NODES + 8;         // 262144
    float* out    = (float*)d_out;

    // one memset covers degi + cnt + facc (contiguous)
    hipMemsetAsync(degi, 0, (2 * N_NODES) * sizeof(int) + DIM * sizeof(float), stream);

    // ---- graph preprocessing: degrees, norm, CSR by target ----
    k_deg<<<N_EDGES / 256, 256, 0, stream>>>(cols, degi);
    k_scan<<<1, 1024, 0, stream>>>(degi, rowptr, dinv);
    k_fill<<<N_EDGES / 256, 256, 0, stream>>>(rows, cols, rowptr, cnt, srcs);

    // ---- GCN layer 1: e1 = relu(conv(x, W1, b1)) ----
    k_gemm<<<N_NODES / 32, 256, 0, stream>>>(x, W1, dinv, buf0);
    k_gather<<<N_NODES / 4, 256, 0, stream>>>(buf0, srcs, rowptr, dinv, b1, buf1);

    // ---- GCN layer 2 gather fused with fc1 partial accumulation ----
    k_gemm<<<N_NODES / 32, 256, 0, stream>>>(buf1, W2, dinv, buf0);
    k_gfc<<<N_NODES / 4, 256, 0, stream>>>(buf0, srcs, rowptr, dinv, b2, fc1_w, facc);

    // ---- MLP tail ----
    k_tail<<<1, 128, 0, stream>>>(facc, fc1_b, fc2_w, fc2_b, fc3_w, fc3_b, out);
}